// Round 4
// baseline (3719.772 us; speedup 1.0000x reference)
//
#include <hip/hip_runtime.h>

// LSTM last-hidden + projection. B=256, T=4096, F=32, H=128, 4H=512.
// 64 WGs x 512 threads (8 waves, 2/SIMD, 1 WG/CU); WG g owns batches [4g,4g+4)
// at MFMA A-rows {0,4,8,12}. z(4x512) = [x_t|h](4x160) @ [W;U](160x512),
// mfma 16x16x32 f16.
// Model: MFMA issue ~19.4cy/SIMD, dependent-use latency L~240cy, VALU-reads of
// MFMA dests ~26.5cy. MfmaUtil ~30% on active CUs => latency-bound serial chain.
// R5 (2890us): per gate TWO depth-2 chains joined with ONE add; chainP seeded
//   C=accX (x·W+bias), chainQ seeded C=0; x double-prefetched.
// R6 (chain reorder + lgkm barrier bundle): REGRESSED 3010 -> reverted.
// R7 (2780us): log2e folded into W/U/b (-L2E i,f,o; +2L2E g), cell state
//   pre-scaled by 2log2e, bare v_exp_f32 everywhere. CONFIRMED -3.6%.
// R8 (this): software-pipeline accX one step ahead. accX(t+1) issued at the
//   HEAD of iter t inside the ds_read shadow (~120cy, previously empty), from
//   xf_next pre-converted in iter t-1. Pre-barrier region shrinks by ~95cy
//   (8 cvts + 4 MFMA issues moved off the act->barrier path). Math identical.

#define TT 4096
#define FF 32
#define HH 128
#define NG 512

typedef float f32x4 __attribute__((ext_vector_type(4)));
typedef _Float16 h16x8 __attribute__((ext_vector_type(8)));

#if __has_builtin(__builtin_amdgcn_exp2f)
#define EX2(v) __builtin_amdgcn_exp2f(v)
#else
#define EX2(v) exp2f(v)
#endif
#define RCP(v) __builtin_amdgcn_rcpf(v)

__global__ __launch_bounds__(512, 2)
void lstm_seq_kernel(const float* __restrict__ x,        // (B,T,F)
                     const int*   __restrict__ seq_lens, // (B)
                     const float* __restrict__ W,        // (F,4H)
                     const float* __restrict__ U,        // (H,4H)
                     const float* __restrict__ bias,     // (4H)
                     const float* __restrict__ Wf,       // (H)
                     const float* __restrict__ bfp,      // (1)
                     float* __restrict__ out)            // (B)
{
    // h-only A staging: A[par][kc-1][slot][j] == A[m=slot&15][k=kc*32+(slot>>4)*8+j]
    __shared__ _Float16 A[2][4][64][8];
    __shared__ float outAcc[4];

    const int tid  = threadIdx.x;
    const int lane = tid & 63;
    const int w    = tid >> 6;     // wave 0..7
    const int c    = lane & 15;    // n-col within tile
    const int q    = lane >> 4;    // quad 0..3 -> this lane's batch
    const int b0   = blockIdx.x * 4;
    const int hc   = w * 16 + c;   // this lane's LSTM cell (0..127)

    {
        _Float16* p = &A[0][0][0][0];
        for (int i = tid; i < 2 * 4 * 64 * 8; i += 512) p[i] = (_Float16)0.f;
        if (tid < 4) outAcc[tid] = 0.f;
    }

    const int sl0 = seq_lens[b0 + 0], sl1 = seq_lens[b0 + 1];
    const int sl2 = seq_lens[b0 + 2], sl3 = seq_lens[b0 + 3];
    const int gmax = max(max(sl0, sl1), max(sl2, sl3));
    const int slq  = seq_lens[b0 + q];

    const float L2E = 1.44269504f;      // log2(e)
    const float K2  = 2.88539008f;      // 2*log2(e)

    // register-resident weights: wave w -> tiles {8j+w}, j = gate i,f,g,o; n = j*128+hc
    // B-frag: lane holds B[k = kc*32 + q*8 + e][n]
    // Columns pre-scaled: i,f,o by -L2E (sigmoid via bare exp2), g by +2*L2E
    // (tanh via bare exp2).
    h16x8 bh[4][5];
    #pragma unroll
    for (int j = 0; j < 4; ++j) {
        const int n = j * 128 + hc;
        const float gsc = (j == 2) ? K2 : -L2E;
        #pragma unroll
        for (int kc = 0; kc < 5; ++kc) {
            #pragma unroll
            for (int e = 0; e < 8; ++e) {
                const int k = kc * 32 + q * 8 + e;
                float v = (k < FF) ? W[k * NG + n] : U[(k - FF) * NG + n];
                bh[j][kc][e] = (_Float16)(v * gsc);
            }
        }
    }

    // bias folded into accX's C operand (only element [0] is ever read), pre-scaled
    f32x4 biasC[4];
    #pragma unroll
    for (int j = 0; j < 4; ++j) {
        const float gsc = (j == 2) ? K2 : -L2E;
        const float bv = bias[j * HH + hc] * gsc;
        f32x4 t = {bv, bv, bv, bv};
        biasC[j] = t;
    }
    const float wfv = Wf[hc];
    const int kk    = FF + hc;                        // K-position of this h element
    const int wkc   = (kk >> 5) - 1;                  // 0..3
    const int wslot = ((kk >> 3) & 3) * 16 + 4 * q;   // batch q at row 4q
    const int wj    = kk & 7;

    // x A-fragment: lane needs A[m=c][k=q*8+e]; real rows m=4b -> lanes c%4==0, batch=c>>2
    const bool xact = ((c & 3) == 0);
    const float* xrow = x + (size_t)(b0 + (c >> 2)) * TT * FF + q * 8;

    const f32x4 zero4 = {0.f, 0.f, 0.f, 0.f};

    // ---- software pipeline state ----
    // accX    : z_x(t)   (ready; consumed as chainP seed this iteration)
    // xf_next : cvt(x_{t+1})  (feeds accX2 = z_x(t+1) issued at iter head)
    // cxa/cxb : raw x_{t+2}   (converted to xf_next at end of this iteration)
    f32x4 accX[4];
    {
        float4 xa = {0,0,0,0}, xb = {0,0,0,0};
        if (xact) {
            xa = *(const float4*)(xrow);
            xb = *(const float4*)(xrow + 4);
        }
        h16x8 xf = { (_Float16)xa.x, (_Float16)xa.y, (_Float16)xa.z, (_Float16)xa.w,
                     (_Float16)xb.x, (_Float16)xb.y, (_Float16)xb.z, (_Float16)xb.w };
        #pragma unroll
        for (int j = 0; j < 4; ++j)
            accX[j] = __builtin_amdgcn_mfma_f32_16x16x32_f16(xf, bh[j][0], biasC[j], 0, 0, 0);
    }
    h16x8 xf_next;
    {
        float4 ya = {0,0,0,0}, yb = {0,0,0,0};
        if (xact) {
            const float* p = xrow + (size_t)1 * FF;   // x_1 (TT=4096 > 1)
            ya = *(const float4*)(p);
            yb = *(const float4*)(p + 4);
        }
        xf_next = (h16x8){ (_Float16)ya.x, (_Float16)ya.y, (_Float16)ya.z, (_Float16)ya.w,
                           (_Float16)yb.x, (_Float16)yb.y, (_Float16)yb.z, (_Float16)yb.w };
    }
    float4 cxa = {0,0,0,0}, cxb = {0,0,0,0};    // x_{t+2}
    if (xact) {
        const float* p = xrow + (size_t)2 * FF;
        cxa = *(const float4*)(p);
        cxb = *(const float4*)(p + 4);
    }
    __syncthreads();

    float cs = 0.f, hh = 0.f;   // cs = 2*log2e * c  (pre-scaled cell state)

    for (int t = 0; t < gmax; ++t) {
        const int par = t & 1, pnx = par ^ 1;

        // post-barrier: h A-fragments (4 x ds_read_b128)
        h16x8 a1 = *(const h16x8*)&A[par][0][lane][0];
        h16x8 a2 = *(const h16x8*)&A[par][1][lane][0];
        h16x8 a3 = *(const h16x8*)&A[par][2][lane][0];
        h16x8 a4 = *(const h16x8*)&A[par][3][lane][0];

        // accX2 = z_x(t+1): register-only operands -> issues inside the
        // ds_read shadow; result needed only next iteration.
        f32x4 accX2[4];
        #pragma unroll
        for (int j = 0; j < 4; ++j)
            accX2[j] = __builtin_amdgcn_mfma_f32_16x16x32_f16(xf_next, bh[j][0], biasC[j], 0, 0, 0);

        // issue x_{t+3} load (covered by a full step, > HBM latency)
        float4 nxa = {0,0,0,0}, nxb = {0,0,0,0};
        if (xact) {
            const int tl = (t + 3 < TT) ? (t + 3) : (TT - 1);
            const float* p = xrow + (size_t)tl * FF;
            nxa = *(const float4*)(p);
            nxb = *(const float4*)(p + 4);
        }

        // two depth-2 chains per gate; all 8 first-links independent (R5 order)
        f32x4 pc[4], qc[4];
        #pragma unroll
        for (int j = 0; j < 4; ++j)
            qc[j] = __builtin_amdgcn_mfma_f32_16x16x32_f16(a3, bh[j][3], zero4, 0, 0, 0);
        #pragma unroll
        for (int j = 0; j < 4; ++j)
            pc[j] = __builtin_amdgcn_mfma_f32_16x16x32_f16(a1, bh[j][1], accX[j], 0, 0, 0);
        #pragma unroll
        for (int j = 0; j < 4; ++j)
            qc[j] = __builtin_amdgcn_mfma_f32_16x16x32_f16(a4, bh[j][4], qc[j], 0, 0, 0);
        #pragma unroll
        for (int j = 0; j < 4; ++j)
            pc[j] = __builtin_amdgcn_mfma_f32_16x16x32_f16(a2, bh[j][2], pc[j], 0, 0, 0);

        // join (8 VALU reads of MFMA dests) + activation; row 4q+0 = batch q
        // z pre-scaled: i,f,o by -L2E -> sigmoid = rcp(1+exp2(z));
        // g by +2*L2E -> gg' = K2*tanh = fmaf(-2K2, rcp(exp2(z)+1), K2).
        float z0 = pc[0][0] + qc[0][0];
        float z1 = pc[1][0] + qc[1][0];
        float z2 = pc[2][0] + qc[2][0];
        float z3 = pc[3][0] + qc[3][0];

        float gi = RCP(1.f + EX2(z0));
        float gf = RCP(1.f + EX2(z1));
        float gg = fmaf(-2.f * K2, RCP(EX2(z2) + 1.f), K2);   // = K2*tanh
        float go = RCP(1.f + EX2(z3));
        float csn = fmaf(gf, cs, gi * gg);                    // scaled c_new (=K2*c_new)
        float th  = fmaf(-2.f, RCP(EX2(csn) + 1.f), 1.f);     // tanh(c_new)
        float hn  = go * th;
        const bool upd = (t < slq);
        cs = upd ? csn : cs;
        hh = upd ? hn : hh;
        A[pnx][wkc][wslot][wj] = (_Float16)hh;

        // rotate pipeline state (off critical path; fills activation stall slots)
        xf_next = (h16x8){ (_Float16)cxa.x, (_Float16)cxa.y, (_Float16)cxa.z, (_Float16)cxa.w,
                           (_Float16)cxb.x, (_Float16)cxb.y, (_Float16)cxb.z, (_Float16)cxb.w };
        #pragma unroll
        for (int j = 0; j < 4; ++j) accX[j] = accX2[j];
        cxa = nxa; cxb = nxb;

        __syncthreads();
    }

    // epilogue: out[b] = h @ Wf + bf
    float p = hh * wfv;
    p += __shfl_down(p, 8, 16);
    p += __shfl_down(p, 4, 16);
    p += __shfl_down(p, 2, 16);
    p += __shfl_down(p, 1, 16);
    if (c == 0) atomicAdd(&outAcc[q], p);
    __syncthreads();
    if (tid < 4) out[b0 + tid] = outAcc[tid] + bfp[0];
}

extern "C" void kernel_launch(void* const* d_in, const int* in_sizes, int n_in,
                              void* d_out, int out_size, void* d_ws, size_t ws_size,
                              hipStream_t stream) {
    const float* x        = (const float*)d_in[0];
    const int*   seq_lens = (const int*)d_in[1];
    const float* W        = (const float*)d_in[2];
    const float* U        = (const float*)d_in[3];
    const float* bias     = (const float*)d_in[4];
    const float* Wf       = (const float*)d_in[5];
    const float* bfp      = (const float*)d_in[6];
    float* out = (float*)d_out;

    lstm_seq_kernel<<<dim3(64), dim3(512), 0, stream>>>(x, seq_lens, W, U, bias, Wf, bfp, out);
}

// Round 5
// 2573.588 us; speedup vs baseline: 1.4454x; 1.4454x over previous
//
#include <hip/hip_runtime.h>

// LSTM last-hidden + projection. B=256, T=4096, F=32, H=128, 4H=512.
// 64 WGs x 512 threads (8 waves, 2/SIMD, 1 WG/CU); WG g owns batches [4g,4g+4)
// at MFMA A-rows {0,4,8,12}. z(4x512) = [x_t|h](4x160) @ [W;U](160x512),
// mfma 16x16x32 f16.
// Model: MFMA issue ~19.4cy/SIMD, dep-use latency L~240cy, VALU-read of an
// MFMA dest ~26.5cy (R4, re-confirmed by R8).
// R5 (2890us): per gate TWO depth-2 chains joined with ONE add; chainP seeded
//   C=accX (x·W+bias), chainQ seeded C=0; x double-prefetched.
// R6 (chain reorder + lgkm barrier): REGRESSED 3010 -> reverted.
// R7 (2780us): log2e folded into W/U/b (-L2E i,f,o; +2L2E g); cell state
//   pre-scaled by 2log2e; bare v_exp_f32. CONFIRMED.
// R8 (3600us): accX pipelined one step ahead BUT rotated via accX=accX2 copy:
//   16 VALU reads of MFMA dests = +481cy/step. Mechanism untested, copy tax.
// R9 (this): same pipeline, NO copies — loop unrolled x2, ping-pong accXa/accXb
//   (even step consumes accXa & produces accXb; odd step reversed). z_x(t+1)
//   issues at the head inside the ds_read shadow; pre-barrier region is only
//   {act, ds_write, cvt, ptr swap}. par becomes compile-time. Math == R7.

#define TT 4096
#define FF 32
#define HH 128
#define NG 512

typedef float f32x4 __attribute__((ext_vector_type(4)));
typedef _Float16 h16x8 __attribute__((ext_vector_type(8)));

#if __has_builtin(__builtin_amdgcn_exp2f)
#define EX2(v) __builtin_amdgcn_exp2f(v)
#else
#define EX2(v) exp2f(v)
#endif
#define RCP(v) __builtin_amdgcn_rcpf(v)

__global__ __launch_bounds__(512, 2)
void lstm_seq_kernel(const float* __restrict__ x,        // (B,T,F)
                     const int*   __restrict__ seq_lens, // (B)
                     const float* __restrict__ W,        // (F,4H)
                     const float* __restrict__ U,        // (H,4H)
                     const float* __restrict__ bias,     // (4H)
                     const float* __restrict__ Wf,       // (H)
                     const float* __restrict__ bfp,      // (1)
                     float* __restrict__ out)            // (B)
{
    // h-only A staging: A[par][kc-1][slot][j] == A[m=slot&15][k=kc*32+(slot>>4)*8+j]
    __shared__ _Float16 A[2][4][64][8];
    __shared__ float outAcc[4];

    const int tid  = threadIdx.x;
    const int lane = tid & 63;
    const int w    = tid >> 6;     // wave 0..7
    const int c    = lane & 15;    // n-col within tile
    const int q    = lane >> 4;    // quad 0..3 -> this lane's batch
    const int b0   = blockIdx.x * 4;
    const int hc   = w * 16 + c;   // this lane's LSTM cell (0..127)

    {
        _Float16* p = &A[0][0][0][0];
        for (int i = tid; i < 2 * 4 * 64 * 8; i += 512) p[i] = (_Float16)0.f;
        if (tid < 4) outAcc[tid] = 0.f;
    }

    const int sl0 = seq_lens[b0 + 0], sl1 = seq_lens[b0 + 1];
    const int sl2 = seq_lens[b0 + 2], sl3 = seq_lens[b0 + 3];
    const int gmax = max(max(sl0, sl1), max(sl2, sl3));
    const int slq  = seq_lens[b0 + q];

    const float L2E = 1.44269504f;      // log2(e)
    const float K2  = 2.88539008f;      // 2*log2(e)

    // register-resident weights: wave w -> tiles {8j+w}, j = gate i,f,g,o; n = j*128+hc
    // B-frag: lane holds B[k = kc*32 + q*8 + e][n]
    // Columns pre-scaled: i,f,o by -L2E (sigmoid via bare exp2), g by +2*L2E.
    h16x8 bh[4][5];
    #pragma unroll
    for (int j = 0; j < 4; ++j) {
        const int n = j * 128 + hc;
        const float gsc = (j == 2) ? K2 : -L2E;
        #pragma unroll
        for (int kc = 0; kc < 5; ++kc) {
            #pragma unroll
            for (int e = 0; e < 8; ++e) {
                const int k = kc * 32 + q * 8 + e;
                float v = (k < FF) ? W[k * NG + n] : U[(k - FF) * NG + n];
                bh[j][kc][e] = (_Float16)(v * gsc);
            }
        }
    }

    // bias folded into accX's C operand (only element [0] is ever read), pre-scaled
    f32x4 biasC[4];
    #pragma unroll
    for (int j = 0; j < 4; ++j) {
        const float gsc = (j == 2) ? K2 : -L2E;
        const float bv = bias[j * HH + hc] * gsc;
        f32x4 t = {bv, bv, bv, bv};
        biasC[j] = t;
    }
    const float wfv = Wf[hc];
    const int kk    = FF + hc;                        // K-position of this h element
    const int wkc   = (kk >> 5) - 1;                  // 0..3
    const int wslot = ((kk >> 3) & 3) * 16 + 4 * q;   // batch q at row 4q
    const int wj    = kk & 7;

    // x A-fragment: lane needs A[m=c][k=q*8+e]; real rows m=4b -> lanes c%4==0, batch=c>>2
    const bool xact = ((c & 3) == 0);
    const float* xrow = x + (size_t)(b0 + (c >> 2)) * TT * FF + q * 8;

    const f32x4 zero4 = {0.f, 0.f, 0.f, 0.f};

    // ---- software pipeline state (no inter-buffer copies; ping-pong) ----
    // accXa/accXb : z_x for alternating steps
    // xf_next     : cvt(x_{t+1}), feeds the head-issued z_x(t+1)
    // cxa/cxb     : raw x_{t+2}
    f32x4 accXa[4], accXb[4];
    h16x8 xf_next;
    {
        float4 xa = {0,0,0,0}, xb = {0,0,0,0};
        if (xact) {
            xa = *(const float4*)(xrow);
            xb = *(const float4*)(xrow + 4);
        }
        h16x8 xf = { (_Float16)xa.x, (_Float16)xa.y, (_Float16)xa.z, (_Float16)xa.w,
                     (_Float16)xb.x, (_Float16)xb.y, (_Float16)xb.z, (_Float16)xb.w };
        #pragma unroll
        for (int j = 0; j < 4; ++j)
            accXa[j] = __builtin_amdgcn_mfma_f32_16x16x32_f16(xf, bh[j][0], biasC[j], 0, 0, 0);
    }
    {
        float4 ya = {0,0,0,0}, yb = {0,0,0,0};
        if (xact) {
            const float* p = xrow + (size_t)1 * FF;   // x_1
            ya = *(const float4*)(p);
            yb = *(const float4*)(p + 4);
        }
        xf_next = (h16x8){ (_Float16)ya.x, (_Float16)ya.y, (_Float16)ya.z, (_Float16)ya.w,
                           (_Float16)yb.x, (_Float16)yb.y, (_Float16)yb.z, (_Float16)yb.w };
    }
    float4 cxa = {0,0,0,0}, cxb = {0,0,0,0};    // x_{t+2}
    if (xact) {
        const float* p = xrow + (size_t)2 * FF;
        cxa = *(const float4*)(p);
        cxb = *(const float4*)(p + 4);
    }
    __syncthreads();

    float cs = 0.f, hh = 0.f;   // cs = 2*log2e * c  (pre-scaled cell state)

    // One LSTM step. PAR: compile-time parity (LDS buffer). AXIN consumed as
    // chainP seed; AXOUT produced at the head (z_x for the NEXT step) inside
    // the ds_read shadow. Ends with __syncthreads().
#define LSTM_STEP(PAR, AXIN, AXOUT, TCUR)                                        \
    {                                                                            \
        h16x8 a1 = *(const h16x8*)&A[PAR][0][lane][0];                           \
        h16x8 a2 = *(const h16x8*)&A[PAR][1][lane][0];                           \
        h16x8 a3 = *(const h16x8*)&A[PAR][2][lane][0];                           \
        h16x8 a4 = *(const h16x8*)&A[PAR][3][lane][0];                           \
        _Pragma("unroll")                                                        \
        for (int j = 0; j < 4; ++j)                                              \
            AXOUT[j] = __builtin_amdgcn_mfma_f32_16x16x32_f16(xf_next, bh[j][0], biasC[j], 0, 0, 0); \
        float4 nxa = {0,0,0,0}, nxb = {0,0,0,0};                                 \
        if (xact) {                                                              \
            const int tl = ((TCUR) + 3 < TT) ? ((TCUR) + 3) : (TT - 1);          \
            const float* p = xrow + (size_t)tl * FF;                             \
            nxa = *(const float4*)(p);                                           \
            nxb = *(const float4*)(p + 4);                                       \
        }                                                                        \
        f32x4 pc[4], qc[4];                                                      \
        _Pragma("unroll")                                                        \
        for (int j = 0; j < 4; ++j)                                              \
            qc[j] = __builtin_amdgcn_mfma_f32_16x16x32_f16(a3, bh[j][3], zero4, 0, 0, 0); \
        _Pragma("unroll")                                                        \
        for (int j = 0; j < 4; ++j)                                              \
            pc[j] = __builtin_amdgcn_mfma_f32_16x16x32_f16(a1, bh[j][1], AXIN[j], 0, 0, 0); \
        _Pragma("unroll")                                                        \
        for (int j = 0; j < 4; ++j)                                              \
            qc[j] = __builtin_amdgcn_mfma_f32_16x16x32_f16(a4, bh[j][4], qc[j], 0, 0, 0); \
        _Pragma("unroll")                                                        \
        for (int j = 0; j < 4; ++j)                                              \
            pc[j] = __builtin_amdgcn_mfma_f32_16x16x32_f16(a2, bh[j][2], pc[j], 0, 0, 0); \
        float z0 = pc[0][0] + qc[0][0];                                          \
        float z1 = pc[1][0] + qc[1][0];                                          \
        float z2 = pc[2][0] + qc[2][0];                                          \
        float z3 = pc[3][0] + qc[3][0];                                          \
        float gi = RCP(1.f + EX2(z0));                                           \
        float gf = RCP(1.f + EX2(z1));                                           \
        float gg = fmaf(-2.f * K2, RCP(EX2(z2) + 1.f), K2);                      \
        float go = RCP(1.f + EX2(z3));                                           \
        float csn = fmaf(gf, cs, gi * gg);                                       \
        float th  = fmaf(-2.f, RCP(EX2(csn) + 1.f), 1.f);                        \
        float hn  = go * th;                                                     \
        const bool upd = ((TCUR) < slq);                                         \
        cs = upd ? csn : cs;                                                     \
        hh = upd ? hn : hh;                                                      \
        A[(PAR) ^ 1][wkc][wslot][wj] = (_Float16)hh;                             \
        xf_next = (h16x8){ (_Float16)cxa.x, (_Float16)cxa.y, (_Float16)cxa.z, (_Float16)cxa.w, \
                           (_Float16)cxb.x, (_Float16)cxb.y, (_Float16)cxb.z, (_Float16)cxb.w }; \
        cxa = nxa; cxb = nxb;                                                    \
        __syncthreads();                                                         \
    }

    int t = 0;
    for (; t + 1 < gmax; t += 2) {
        LSTM_STEP(0, accXa, accXb, t)
        LSTM_STEP(1, accXb, accXa, t + 1)
    }
    if (t < gmax) {          // gmax odd: one final even-parity step
        LSTM_STEP(0, accXa, accXb, t)
    }
#undef LSTM_STEP

    // epilogue: out[b] = h @ Wf + bf
    float p = hh * wfv;
    p += __shfl_down(p, 8, 16);
    p += __shfl_down(p, 4, 16);
    p += __shfl_down(p, 2, 16);
    p += __shfl_down(p, 1, 16);
    if (c == 0) atomicAdd(&outAcc[q], p);
    __syncthreads();
    if (tid < 4) out[b0 + tid] = outAcc[tid] + bfp[0];
}

extern "C" void kernel_launch(void* const* d_in, const int* in_sizes, int n_in,
                              void* d_out, int out_size, void* d_ws, size_t ws_size,
                              hipStream_t stream) {
    const float* x        = (const float*)d_in[0];
    const int*   seq_lens = (const int*)d_in[1];
    const float* W        = (const float*)d_in[2];
    const float* U        = (const float*)d_in[3];
    const float* bias     = (const float*)d_in[4];
    const float* Wf       = (const float*)d_in[5];
    const float* bfp      = (const float*)d_in[6];
    float* out = (float*)d_out;

    lstm_seq_kernel<<<dim3(64), dim3(512), 0, stream>>>(x, seq_lens, W, U, bias, Wf, bfp, out);
}

// Round 6
// 2495.102 us; speedup vs baseline: 1.4908x; 1.0315x over previous
//
#include <hip/hip_runtime.h>

// LSTM last-hidden + projection. B=256, T=4096, F=32, H=128, 4H=512.
// 64 WGs x 512 threads (8 waves, 2/SIMD, 1 WG/CU); WG g owns batches [4g,4g+4)
// at MFMA A-rows {0,4,8,12}. z(4x512) = [x_t|h](4x160) @ [W;U](160x512),
// mfma 16x16x32 f16.
// Model: MFMA issue ~19.4cy/SIMD, dep-use latency L~240cy, and EVERY
// instruction on the serial act->barrier path ~25cy (R8/R9 evidence).
// R5 (2890us): per gate TWO depth-2 chains joined with ONE add.
// R6 (chain interleave + lgkm barrier): REGRESSED -> link distances must stay.
// R7 (2780us): log2e folded into W/U/b; bare v_exp_f32. CONFIRMED.
// R8 (3600us): accX pipelined but rotated by copy: 16 MFMA-dest reads = +481cy.
// R9 (2455us): ping-pong accXa/accXb (x2 unroll, no copies); z_x(t+1) issued
//   in the ds_read shadow; compile-time par. CONFIRMED -12%.
// R10 (this): tail-trim, DAG-shape-preserving:
//  (1) fold gg-fma into csn and th into hn (-1 level, -1 tail op);
//  (2) within-group gate permutation {2,0,1,3} (g first, o last) — link
//      distance stays 8 slots; join reads in completion order;
//  (3) xf_next cvt rotation moved from tail into the head ds_read shadow.

#define TT 4096
#define FF 32
#define HH 128
#define NG 512

typedef float f32x4 __attribute__((ext_vector_type(4)));
typedef _Float16 h16x8 __attribute__((ext_vector_type(8)));

#if __has_builtin(__builtin_amdgcn_exp2f)
#define EX2(v) __builtin_amdgcn_exp2f(v)
#else
#define EX2(v) exp2f(v)
#endif
#define RCP(v) __builtin_amdgcn_rcpf(v)

__global__ __launch_bounds__(512, 2)
void lstm_seq_kernel(const float* __restrict__ x,        // (B,T,F)
                     const int*   __restrict__ seq_lens, // (B)
                     const float* __restrict__ W,        // (F,4H)
                     const float* __restrict__ U,        // (H,4H)
                     const float* __restrict__ bias,     // (4H)
                     const float* __restrict__ Wf,       // (H)
                     const float* __restrict__ bfp,      // (1)
                     float* __restrict__ out)            // (B)
{
    // h-only A staging: A[par][kc-1][slot][j] == A[m=slot&15][k=kc*32+(slot>>4)*8+j]
    __shared__ _Float16 A[2][4][64][8];
    __shared__ float outAcc[4];

    const int tid  = threadIdx.x;
    const int lane = tid & 63;
    const int w    = tid >> 6;     // wave 0..7
    const int c    = lane & 15;    // n-col within tile
    const int q    = lane >> 4;    // quad 0..3 -> this lane's batch
    const int b0   = blockIdx.x * 4;
    const int hc   = w * 16 + c;   // this lane's LSTM cell (0..127)

    {
        _Float16* p = &A[0][0][0][0];
        for (int i = tid; i < 2 * 4 * 64 * 8; i += 512) p[i] = (_Float16)0.f;
        if (tid < 4) outAcc[tid] = 0.f;
    }

    const int sl0 = seq_lens[b0 + 0], sl1 = seq_lens[b0 + 1];
    const int sl2 = seq_lens[b0 + 2], sl3 = seq_lens[b0 + 3];
    const int gmax = max(max(sl0, sl1), max(sl2, sl3));
    const int slq  = seq_lens[b0 + q];

    const float L2E = 1.44269504f;      // log2(e)
    const float K2  = 2.88539008f;      // 2*log2(e)

    // gate issue order: g first (longest act chain), o last (needed last)
    const int JP[4] = {2, 0, 1, 3};

    // register-resident weights: wave w -> tiles {8j+w}, j = gate i,f,g,o; n = j*128+hc
    // B-frag: lane holds B[k = kc*32 + q*8 + e][n]
    // Columns pre-scaled: i,f,o by -L2E (sigmoid via bare exp2), g by +2*L2E.
    h16x8 bh[4][5];
    #pragma unroll
    for (int j = 0; j < 4; ++j) {
        const int n = j * 128 + hc;
        const float gsc = (j == 2) ? K2 : -L2E;
        #pragma unroll
        for (int kc = 0; kc < 5; ++kc) {
            #pragma unroll
            for (int e = 0; e < 8; ++e) {
                const int k = kc * 32 + q * 8 + e;
                float v = (k < FF) ? W[k * NG + n] : U[(k - FF) * NG + n];
                bh[j][kc][e] = (_Float16)(v * gsc);
            }
        }
    }

    // bias folded into accX's C operand (only element [0] is ever read), pre-scaled
    f32x4 biasC[4];
    #pragma unroll
    for (int j = 0; j < 4; ++j) {
        const float gsc = (j == 2) ? K2 : -L2E;
        const float bv = bias[j * HH + hc] * gsc;
        f32x4 t = {bv, bv, bv, bv};
        biasC[j] = t;
    }
    const float wfv = Wf[hc];
    const int kk    = FF + hc;                        // K-position of this h element
    const int wkc   = (kk >> 5) - 1;                  // 0..3
    const int wslot = ((kk >> 3) & 3) * 16 + 4 * q;   // batch q at row 4q
    const int wj    = kk & 7;

    // x A-fragment: lane needs A[m=c][k=q*8+e]; real rows m=4b -> lanes c%4==0, batch=c>>2
    const bool xact = ((c & 3) == 0);
    const float* xrow = x + (size_t)(b0 + (c >> 2)) * TT * FF + q * 8;

    const f32x4 zero4 = {0.f, 0.f, 0.f, 0.f};

    // ---- software pipeline state (no inter-buffer copies; ping-pong) ----
    f32x4 accXa[4], accXb[4];
    h16x8 xf_next;
    {
        float4 xa = {0,0,0,0}, xb = {0,0,0,0};
        if (xact) {
            xa = *(const float4*)(xrow);
            xb = *(const float4*)(xrow + 4);
        }
        h16x8 xf = { (_Float16)xa.x, (_Float16)xa.y, (_Float16)xa.z, (_Float16)xa.w,
                     (_Float16)xb.x, (_Float16)xb.y, (_Float16)xb.z, (_Float16)xb.w };
        #pragma unroll
        for (int j = 0; j < 4; ++j)
            accXa[j] = __builtin_amdgcn_mfma_f32_16x16x32_f16(xf, bh[j][0], biasC[j], 0, 0, 0);
    }
    {
        float4 ya = {0,0,0,0}, yb = {0,0,0,0};
        if (xact) {
            const float* p = xrow + (size_t)1 * FF;   // x_1
            ya = *(const float4*)(p);
            yb = *(const float4*)(p + 4);
        }
        xf_next = (h16x8){ (_Float16)ya.x, (_Float16)ya.y, (_Float16)ya.z, (_Float16)ya.w,
                           (_Float16)yb.x, (_Float16)yb.y, (_Float16)yb.z, (_Float16)yb.w };
    }
    float4 cxa = {0,0,0,0}, cxb = {0,0,0,0};    // x_{t+2}
    if (xact) {
        const float* p = xrow + (size_t)2 * FF;
        cxa = *(const float4*)(p);
        cxb = *(const float4*)(p + 4);
    }
    __syncthreads();

    float cs = 0.f, hh = 0.f;   // cs = 2*log2e * c  (pre-scaled cell state)

    // One LSTM step. PAR compile-time. AXIN consumed as chainP seed; AXOUT
    // (z_x for next step) + xf_next rotation + x-load all issued at the HEAD
    // inside the ds_read shadow. Tail = join/act/selects/ds_write only.
#define LSTM_STEP(PAR, AXIN, AXOUT, TCUR)                                        \
    {                                                                            \
        h16x8 a1 = *(const h16x8*)&A[PAR][0][lane][0];                           \
        h16x8 a2 = *(const h16x8*)&A[PAR][1][lane][0];                           \
        h16x8 a3 = *(const h16x8*)&A[PAR][2][lane][0];                           \
        h16x8 a4 = *(const h16x8*)&A[PAR][3][lane][0];                           \
        _Pragma("unroll")                                                        \
        for (int jj = 0; jj < 4; ++jj) {                                         \
            const int j = JP[jj];                                                \
            AXOUT[j] = __builtin_amdgcn_mfma_f32_16x16x32_f16(xf_next, bh[j][0], biasC[j], 0, 0, 0); \
        }                                                                        \
        xf_next = (h16x8){ (_Float16)cxa.x, (_Float16)cxa.y, (_Float16)cxa.z, (_Float16)cxa.w, \
                           (_Float16)cxb.x, (_Float16)cxb.y, (_Float16)cxb.z, (_Float16)cxb.w }; \
        float4 nxa = {0,0,0,0}, nxb = {0,0,0,0};                                 \
        if (xact) {                                                              \
            const int tl = ((TCUR) + 3 < TT) ? ((TCUR) + 3) : (TT - 1);          \
            const float* p = xrow + (size_t)tl * FF;                             \
            nxa = *(const float4*)(p);                                           \
            nxb = *(const float4*)(p + 4);                                       \
        }                                                                        \
        f32x4 pc[4], qc[4];                                                      \
        _Pragma("unroll")                                                        \
        for (int jj = 0; jj < 4; ++jj) {                                         \
            const int j = JP[jj];                                                \
            qc[j] = __builtin_amdgcn_mfma_f32_16x16x32_f16(a3, bh[j][3], zero4, 0, 0, 0); \
        }                                                                        \
        _Pragma("unroll")                                                        \
        for (int jj = 0; jj < 4; ++jj) {                                         \
            const int j = JP[jj];                                                \
            pc[j] = __builtin_amdgcn_mfma_f32_16x16x32_f16(a1, bh[j][1], AXIN[j], 0, 0, 0); \
        }                                                                        \
        _Pragma("unroll")                                                        \
        for (int jj = 0; jj < 4; ++jj) {                                         \
            const int j = JP[jj];                                                \
            qc[j] = __builtin_amdgcn_mfma_f32_16x16x32_f16(a4, bh[j][4], qc[j], 0, 0, 0); \
        }                                                                        \
        _Pragma("unroll")                                                        \
        for (int jj = 0; jj < 4; ++jj) {                                         \
            const int j = JP[jj];                                                \
            pc[j] = __builtin_amdgcn_mfma_f32_16x16x32_f16(a2, bh[j][2], pc[j], 0, 0, 0); \
        }                                                                        \
        /* join in completion order; z pre-scaled: i,f,o by -L2E, g by +2L2E */  \
        float z2 = pc[2][0] + qc[2][0];                                          \
        float r2 = RCP(EX2(z2) + 1.f);          /* K2*tanh = K2 - 2K2*r2 */      \
        float z0 = pc[0][0] + qc[0][0];                                          \
        float gi = RCP(EX2(z0) + 1.f);                                           \
        float z1 = pc[1][0] + qc[1][0];                                          \
        float gf = RCP(EX2(z1) + 1.f);                                           \
        float z3 = pc[3][0] + qc[3][0];                                          \
        float go = RCP(EX2(z3) + 1.f);                                           \
        float csn = fmaf(gi * (-2.f * K2), r2, fmaf(gi, K2, gf * cs));           \
        float rc  = RCP(EX2(csn) + 1.f);                                         \
        float hn  = fmaf(-2.f * go, rc, go);    /* go * tanh(c_new) */           \
        const bool upd = ((TCUR) < slq);                                         \
        cs = upd ? csn : cs;                                                     \
        hh = upd ? hn : hh;                                                      \
        A[(PAR) ^ 1][wkc][wslot][wj] = (_Float16)hh;                             \
        cxa = nxa; cxb = nxb;                                                    \
        __syncthreads();                                                         \
    }

    int t = 0;
    for (; t + 1 < gmax; t += 2) {
        LSTM_STEP(0, accXa, accXb, t)
        LSTM_STEP(1, accXb, accXa, t + 1)
    }
    if (t < gmax) {          // gmax odd: one final even-parity step
        LSTM_STEP(0, accXa, accXb, t)
    }
#undef LSTM_STEP

    // epilogue: out[b] = h @ Wf + bf
    float p = hh * wfv;
    p += __shfl_down(p, 8, 16);
    p += __shfl_down(p, 4, 16);
    p += __shfl_down(p, 2, 16);
    p += __shfl_down(p, 1, 16);
    if (c == 0) atomicAdd(&outAcc[q], p);
    __syncthreads();
    if (tid < 4) out[b0 + tid] = outAcc[tid] + bfp[0];
}

extern "C" void kernel_launch(void* const* d_in, const int* in_sizes, int n_in,
                              void* d_out, int out_size, void* d_ws, size_t ws_size,
                              hipStream_t stream) {
    const float* x        = (const float*)d_in[0];
    const int*   seq_lens = (const int*)d_in[1];
    const float* W        = (const float*)d_in[2];
    const float* U        = (const float*)d_in[3];
    const float* bias     = (const float*)d_in[4];
    const float* Wf       = (const float*)d_in[5];
    const float* bfp      = (const float*)d_in[6];
    float* out = (float*)d_out;

    lstm_seq_kernel<<<dim3(64), dim3(512), 0, stream>>>(x, seq_lens, W, U, bias, Wf, bfp, out);
}